// Round 12
// baseline (199.245 us; speedup 1.0000x reference)
//
#include <hip/hip_runtime.h>

#define T_ 30
#define H_ 41
#define WD_ 2048
#define NSEC 9
#define FM 50
#define WP 502
#define THRESH 23.0f
#define POOLED_SIZE (NSEC * T_ * FM * WP)   // 6,777,000
#define MARGIN 0.125f                       // >> realistic f16 max error (~0.0125)
#define NFRAG 18432                         // 9 sec * 64 fm * 32 tap-octets
#define RSTR 344                            // row stride (elems): 176 + 24*7 = 344
#define PSTR (10 * RSTR)                    // plane stride

typedef _Float16 half8 __attribute__((ext_vector_type(8)));
typedef _Float16 half4v __attribute__((ext_vector_type(4)));
typedef float f32x4 __attribute__((ext_vector_type(4)));

__device__ __forceinline__ unsigned short f16_bits(float f) {
    union { _Float16 h; unsigned short s; } u;
    u.h = (_Float16)f;
    return u.s;
}

// ---------------- prep: W -> MFMA-ready f16 fragments in ws ---------------
__global__ __launch_bounds__(256) void prep_kernel(
    const float* __restrict__ Wg, int* __restrict__ wsi,
    uint4* __restrict__ wfh)
{
    const int gid = blockIdx.x * 256 + threadIdx.x;
    if (gid < NSEC) wsi[gid] = 0x7fffffff;
    if (gid >= NFRAG) return;
    const int blk = gid & 31;
    const int fm  = (gid >> 5) & 63;
    const int sec = gid >> 11;
    const int t0  = blk * 8;
    const bool valid = (t0 < 240) && (fm < FM);
    const float* wp = Wg + ((size_t)sec * FM + (valid ? fm : 0)) * 240 + (valid ? t0 : 0);
    float4 wa = *reinterpret_cast<const float4*>(wp);
    float4 wb = *reinterpret_cast<const float4*>(wp + 4);
    float f[8] = {wa.x, wa.y, wa.z, wa.w, wb.x, wb.y, wb.z, wb.w};
    unsigned hh[4];
#pragma unroll
    for (int i = 0; i < 4; ++i) {
        unsigned h0 = f16_bits(valid ? f[2 * i] : 0.f);
        unsigned h1 = f16_bits(valid ? f[2 * i + 1] : 0.f);
        hh[i] = (h1 << 16) | h0;
    }
    wfh[gid] = *reinterpret_cast<uint4*>(hh);
}

// ---------------- Kernel A: f16 MFMA conv + fire/pool/argmin --------------
// R21 = R20 + two register-co-designed changes (must stay <= 64 VGPR -- the
// m69 pool cliff: 65 VGPR halves waves/CU 16->8, the R17 regression):
//  (1) ADDITIVE-ROTATION swizzle replaces XOR: phys = row*344 + 24*(row&7)+s.
//      Rotation preserves octet adjacency, so the off-4/off-8 reads are
//      constant immediates off ONE pA base: pB[8] array (8 VGPR) + its
//      address VALU deleted. Bank spread: 12 banks * (row&7), 8 distinct.
//  (2) DEFERRED-MAX epilogue (R17's -42kcyc VALU, now register-neutral:
//      vmax's +8 VGPR paid by pB's -8): per ft accumulate vmax over S
//      (8 fmax/S), 8 checks/ft after the S loop (was 32). Monotone
//      set-only group repair: vmax>=23+M certain spike; <=23-M certain
//      none (vmax is the max); else wave-parallel exact recompute of the
//      4 group cols, SET-ONLY (R19 OR-violation lesson). Group validity
//      uniform: pcgb mult of 4 -> pcgb<=2007 covers all 4 cols exactly.
template <bool PRE>
__global__ __launch_bounds__(256) void conv_pool_kernel(
    const float* __restrict__ x, const float* __restrict__ Wg,
    const uint4* __restrict__ wfh,
    float* __restrict__ out, int* __restrict__ keys)
{
    __shared__ __align__(16) unsigned short xh[4 * PSTR];     // 27.5 KB (f16)
    __shared__ int sred[256];                                  // lmask, then red

    const int b       = blockIdx.x;
    const int coltile = b & 15;
    const int tt      = (b >> 4) % T_;
    const int sec     = b / 480;
    const int w0      = coltile * 128;     // pot-col base
    const int rowbase = 4 * sec;
    const int tid     = threadIdx.x;

    // ---- stage x: 10 rows x 176 cols -> f16, 4 shifted planes, rotated ----
    for (int i = tid; i < 440; i += 256) {
        const int row = i / 44;
        const int c4  = i % 44;
        const int grow = (rowbase + row < H_) ? rowbase + row : H_ - 1;
        const int gc   = w0 + 4 * c4;
        float4 v;
        if (gc + 3 < WD_) {
            v = *reinterpret_cast<const float4*>(x + ((size_t)tt * H_ + grow) * WD_ + gc);
        } else {
            v.x = v.y = v.z = v.w = 0.f;
        }
        float f[4] = {v.x, v.y, v.z, v.w};
        unsigned short hq[4];
#pragma unroll
        for (int e = 0; e < 4; ++e) hq[e] = f16_bits(f[e]);
        const int rbase = row * RSTR + 24 * (row & 7);
#pragma unroll
        for (int S = 0; S < 4; ++S)
#pragma unroll
            for (int e = 0; e < 4; ++e) {
                const int j = 4 * c4 + e - S;
                if (j >= 0 && j < 176) xh[S * PSTR + rbase + j] = hq[e];
            }
    }
    __syncthreads();

    const int L    = tid & 63;
    const int j_p  = tid >> 6;       // wave id = pot row
    const int q    = L >> 4;         // quad (K-octet)
    const int n16  = L & 15;         // A: m-index; B: fm-index

    // per-kk tap geometry (tau0 = 32kk + 8q -> weight row r, col c0), rotated
    int pA[8];
#pragma unroll
    for (int kk = 0; kk < 8; ++kk) {
        const int t0 = 32 * kk + 8 * q;
        const int r  = t0 / 40;
        const int c0 = t0 - 40 * r;          // multiple of 8
        const int row = j_p + r;
        pA[kk] = row * RSTR + 24 * (row & 7) + c0 + 8 * n16;   // 16B-aligned
    }

    unsigned mask = 0;

#pragma unroll 1
    for (int ft = 0; ft < 4; ++ft) {
        const int fm = ft * 16 + n16;
        const bool fmv = (fm < FM);
        half8 wh[8];
        if (PRE) {
            const int fb = (sec * 64 + ft * 16 + n16) * 32 + q;
#pragma unroll
            for (int kk = 0; kk < 8; ++kk) {
                union { uint4 u; half8 h; } c1;
                c1.u = wfh[fb + 4 * kk];
                wh[kk] = c1.h;
            }
        } else {
            // fallback: in-kernel build (used only if ws too small)
#pragma unroll
            for (int kk = 0; kk < 8; ++kk) {
                const int t0 = 32 * kk + 8 * q;
                const bool wvalid = (t0 < 240) && (fm < FM);
                const float* wp = Wg + (size_t)sec * FM * 240 +
                                  (size_t)(wvalid ? fm : 0) * 240 + (wvalid ? t0 : 0);
                float4 wa = *reinterpret_cast<const float4*>(wp);
                float4 wb = *reinterpret_cast<const float4*>(wp + 4);
                float f[8] = {wa.x, wa.y, wa.z, wa.w, wb.x, wb.y, wb.z, wb.w};
                union { unsigned u[4]; half8 h; } c1;
#pragma unroll
                for (int i = 0; i < 4; ++i) {
                    unsigned h0 = f16_bits(wvalid ? f[2 * i] : 0.f);
                    unsigned h1 = f16_bits(wvalid ? f[2 * i + 1] : 0.f);
                    c1.u[i] = (h1 << 16) | h0;
                }
                wh[kk] = c1.h;
            }
        }

        f32x4 vmax0 = {-1e30f, -1e30f, -1e30f, -1e30f};   // grp 0: res 0..3
        f32x4 vmax1 = {-1e30f, -1e30f, -1e30f, -1e30f};   // grp 1: res 4..7

#pragma unroll 1
        for (int S = 0; S < 4; ++S) {
            const unsigned short* hb = &xh[S * PSTR];

            f32x4 acc0 = {0.f, 0.f, 0.f, 0.f};   // res = S     (off 0)
            f32x4 acc1 = {0.f, 0.f, 0.f, 0.f};   // res = S + 4 (off 4)
#pragma unroll
            for (int kk = 0; kk < 8; ++kk) {
                half8 ah0 = *reinterpret_cast<const half8*>(hb + pA[kk]);
                half4v h0 = *reinterpret_cast<const half4v*>(hb + pA[kk] + 4);
                half4v h1 = *reinterpret_cast<const half4v*>(hb + pA[kk] + 8);
                half8 ah1 = __builtin_shufflevector(h0, h1, 0, 1, 2, 3, 4, 5, 6, 7);
                acc0 = __builtin_amdgcn_mfma_f32_16x16x32_f16(ah0, wh[kk], acc0, 0, 0, 0);
                acc1 = __builtin_amdgcn_mfma_f32_16x16x32_f16(ah1, wh[kk], acc1, 0, 0, 0);
            }
#pragma unroll
            for (int reg = 0; reg < 4; ++reg) {
                vmax0[reg] = fmaxf(vmax0[reg], acc0[reg]);
                vmax1[reg] = fmaxf(vmax1[reg], acc1[reg]);
            }
        }

        // ---- deferred epilogue: 8 checks/ft; rare set-only group repair ----
        auto depilogue = [&](const f32x4& vmax, const int grp) {
            float d[4];
            float worst = 1e30f;
#pragma unroll
            for (int reg = 0; reg < 4; ++reg) {
                const int pcgb = w0 + grp * 4 + 8 * (q * 4 + reg);
                const bool valid = fmv && (pcgb <= 2007);   // uniform over 4 cols
                const float ev = vmax[reg] - THRESH;
                d[reg] = valid ? __builtin_fabsf(ev) : 1e30f;
                worst = fminf(worst, d[reg]);
                if (valid && ev >= MARGIN)                  // CERTAIN spike only
                    mask |= 1u << (reg * 8 + ft * 2 + grp);
            }
            if (__ballot(worst < MARGIN)) {                 // wave-uniform, rare
#pragma unroll
                for (int reg = 0; reg < 4; ++reg) {
                    unsigned long long bm = __ballot(d[reg] < MARGIN);
                    const unsigned bitv = 1u << (reg * 8 + ft * 2 + grp);
                    while (bm) {
                        const int src = __ffsll((long long)bm) - 1;
                        bm &= bm - 1;
                        const int q_s    = src >> 4;
                        const int fm_s   = ft * 16 + (src & 15);
                        const int pcgb_s = w0 + grp * 4 + 8 * (q_s * 4 + reg);
                        bool any = false;
#pragma unroll 1
                        for (int c = 0; c < 4; ++c) {
                            float part = 0.f;
#pragma unroll
                            for (int k2 = 0; k2 < 4; ++k2) {
                                const int t = L + 64 * k2;
                                if (t < 240) {
                                    const int r2 = t / 40, c2 = t - 40 * r2;
                                    part = fmaf(
                                        x[((size_t)tt * H_ + rowbase + j_p + r2) * WD_ + pcgb_s + c + c2],
                                        Wg[(size_t)sec * FM * 240 + (size_t)fm_s * 240 + t],
                                        part);
                                }
                            }
#pragma unroll
                            for (int off = 32; off; off >>= 1)
                                part += __shfl_xor(part, off);
                            any |= (part > THRESH);         // broadcast on all lanes
                        }
                        if (L == src && any)
                            mask |= bitv;                   // SET-ONLY (monotone OR)
                    }
                }
            }
        };
        depilogue(vmax0, 0);
        depilogue(vmax1, 1);
    }

    unsigned* lmask = reinterpret_cast<unsigned*>(sred);
    lmask[j_p * 64 + L] = mask;
    __syncthreads();

    // ---- cross-wave OR + pooled write + fused first-spike argmin ----
    int mykey = 0x7fffffff;
    for (int e = tid; e < 2048; e += 256) {
        const int fmo = e >> 5, p = e & 31;
        const int m = p >> 1, rg = p & 1, ftc = fmo >> 4, fn = fmo & 15;
        const int lane = (m >> 2) * 16 + fn;
        const int bitpos = (m & 3) * 8 + ftc * 2 + rg;
        const unsigned bits = lmask[0 * 64 + lane] | lmask[1 * 64 + lane] |
                              lmask[2 * 64 + lane] | lmask[3 * 64 + lane];
        const int pg = coltile * 32 + p;
        const int spk = (bits >> bitpos) & 1u;
        if (fmo < FM && pg < WP) {
            out[((size_t)(sec * T_ + tt) * FM + fmo) * WP + pg] = spk ? 1.0f : 0.0f;
            if (spk) mykey = min(mykey, fmo * WP + pg);   // section-flat idx
        }
    }
    __syncthreads();                     // protect lmask -> red reuse
    sred[tid] = mykey;
    __syncthreads();
    for (int s = 128; s > 0; s >>= 1) {
        if (tid < s) sred[tid] = min(sred[tid], sred[tid + s]);
        __syncthreads();
    }
    if (tid == 0 && sred[0] != 0x7fffffff)
        atomicMin(&keys[sec], (tt << 15) | sred[0]);
}

// ---------------- init (fallback only) ----------------
__global__ void init_kernel(int* __restrict__ ws)
{
    if (threadIdx.x < NSEC) ws[threadIdx.x] = 0x7fffffff;
}

// ---------------- Kernel D: finalize winners ----------------
__global__ void finalize_kernel(const int* __restrict__ ws, float* __restrict__ out)
{
    const int i = threadIdx.x;
    if (i < NSEC) {
        const int key = ws[i];
        float feat;
        if (key == 0x7fffffff) feat = -1.0f;
        else                   feat = (float)((key & 32767) / WP);
        out[POOLED_SIZE + i] = feat;
    }
}

extern "C" void kernel_launch(void* const* d_in, const int* in_sizes, int n_in,
                              void* d_out, int out_size, void* d_ws, size_t ws_size,
                              hipStream_t stream) {
    const float* x  = (const float*)d_in[0];
    const float* Wg = (const float*)d_in[1];
    float* out = (float*)d_out;
    int*   wsi = (int*)d_ws;
    uint4* wfh = (uint4*)((char*)d_ws + 256);

    const bool pre = ws_size >= 256 + (size_t)NFRAG * 16;   // ~295 KB
    if (pre) {
        prep_kernel<<<dim3(72), dim3(256), 0, stream>>>(Wg, wsi, wfh);
        conv_pool_kernel<true><<<dim3(4320), dim3(256), 0, stream>>>(x, Wg, wfh, out, wsi);
    } else {
        init_kernel<<<dim3(1), dim3(64), 0, stream>>>(wsi);
        conv_pool_kernel<false><<<dim3(4320), dim3(256), 0, stream>>>(x, Wg, wfh, out, wsi);
    }
    finalize_kernel<<<dim3(1), dim3(16), 0, stream>>>(wsi, out);
}

// Round 13
// 172.842 us; speedup vs baseline: 1.1528x; 1.1528x over previous
//
#include <hip/hip_runtime.h>

#define T_ 30
#define H_ 41
#define WD_ 2048
#define NSEC 9
#define FM 50
#define WP 502
#define THRESH 23.0f
#define POOLED_SIZE (NSEC * T_ * FM * WP)   // 6,777,000
#define MARGIN 0.125f                       // >> realistic f16 max error (~0.02)
#define NFRAG 18432                         // 9 sec * 64 fm * 32 tap-octets

typedef _Float16 half8 __attribute__((ext_vector_type(8)));
typedef _Float16 half4v __attribute__((ext_vector_type(4)));
typedef float f32x4 __attribute__((ext_vector_type(4)));

__device__ __forceinline__ unsigned short f16_bits(float f) {
    union { _Float16 h; unsigned short s; } u;
    u.h = (_Float16)f;
    return u.s;
}

// ---------------- prep: W -> MFMA-ready f16 fragments in ws ---------------
__global__ __launch_bounds__(256) void prep_kernel(
    const float* __restrict__ Wg, int* __restrict__ wsi,
    uint4* __restrict__ wfh)
{
    const int gid = blockIdx.x * 256 + threadIdx.x;
    if (gid < NSEC) wsi[gid] = 0x7fffffff;
    if (gid >= NFRAG) return;
    const int blk = gid & 31;
    const int fm  = (gid >> 5) & 63;
    const int sec = gid >> 11;
    const int t0  = blk * 8;
    const bool valid = (t0 < 240) && (fm < FM);
    const float* wp = Wg + ((size_t)sec * FM + (valid ? fm : 0)) * 240 + (valid ? t0 : 0);
    float4 wa = *reinterpret_cast<const float4*>(wp);
    float4 wb = *reinterpret_cast<const float4*>(wp + 4);
    float f[8] = {wa.x, wa.y, wa.z, wa.w, wb.x, wb.y, wb.z, wb.w};
    unsigned hh[4];
#pragma unroll
    for (int i = 0; i < 4; ++i) {
        unsigned h0 = f16_bits(valid ? f[2 * i] : 0.f);
        unsigned h1 = f16_bits(valid ? f[2 * i + 1] : 0.f);
        hh[i] = (h1 << 16) | h0;
    }
    wfh[gid] = *reinterpret_cast<uint4*>(hh);
}

// ---------------- Kernel A: f16 MFMA conv + fire/pool/argmin --------------
// R22 = R20 (best verified: conv 124us, e2e 173us, VGPR 64) + ONE change:
//   delete the redundant h0 = b64@pA+4 LDS read. Within an octet, XOR by
//   xr (multiple of 8) preserves intra-octet order, so ah0 (b128@pA) is
//   exactly logical [s, s+8) and its upper half == h0. Build
//   ah1 = [s+4, s+12) = shuffle(ah0[4:8], h1) in registers.
//   DS issues/wave 384 -> 256 (DS was the top pipe, ~240 kcyc/CU incl.
//   conflicts); register pressure goes DOWN (one fewer live b64).
//   MFMA operands bit-identical -> absmax 0.
// Register discipline (R17/R21 lessons): NO epilogue deferral, NO extra
// state; must print VGPR <= 64 (the m69 cliff: 65 halves waves/CU).
template <bool PRE>
__global__ __launch_bounds__(256) void conv_pool_kernel(
    const float* __restrict__ x, const float* __restrict__ Wg,
    const uint4* __restrict__ wfh,
    float* __restrict__ out, int* __restrict__ keys)
{
    __shared__ __align__(16) unsigned short xh[4][10][192];   // 15 KB (f16)
    __shared__ int sred[256];                                  // lmask, then red

    const int b       = blockIdx.x;
    const int coltile = b & 15;
    const int tt      = (b >> 4) % T_;
    const int sec     = b / 480;
    const int w0      = coltile * 128;     // pot-col base
    const int rowbase = 4 * sec;
    const int tid     = threadIdx.x;

    // ---- stage x: 10 rows x 176 cols -> f16, 4 shifted planes, swizzled ----
    for (int i = tid; i < 440; i += 256) {
        const int row = i / 44;
        const int c4  = i % 44;
        const int grow = (rowbase + row < H_) ? rowbase + row : H_ - 1;
        const int gc   = w0 + 4 * c4;
        float4 v;
        if (gc + 3 < WD_) {
            v = *reinterpret_cast<const float4*>(x + ((size_t)tt * H_ + grow) * WD_ + gc);
        } else {
            v.x = v.y = v.z = v.w = 0.f;
        }
        float f[4] = {v.x, v.y, v.z, v.w};
        unsigned short hq[4];
#pragma unroll
        for (int e = 0; e < 4; ++e) hq[e] = f16_bits(f[e]);
        const int xr = (row & 7) << 3;
#pragma unroll
        for (int S = 0; S < 4; ++S)
#pragma unroll
            for (int e = 0; e < 4; ++e) {
                const int j = 4 * c4 + e - S;
                if (j >= 0 && j < 176) xh[S][row][j ^ xr] = hq[e];
            }
    }
    __syncthreads();

    const int L    = tid & 63;
    const int j_p  = tid >> 6;       // wave id = pot row
    const int q    = L >> 4;         // quad (K-octet)
    const int n16  = L & 15;         // A: m-index; B: fm-index

    // per-kk tap geometry (tau0 = 32kk + 8q -> weight row r, col c0), swizzled
    int pA[8], pB[8];
#pragma unroll
    for (int kk = 0; kk < 8; ++kk) {
        const int t0 = 32 * kk + 8 * q;
        const int r  = t0 / 40;
        const int c0 = t0 - 40 * r;          // multiple of 8
        const int row = j_p + r;
        const int xr  = (row & 7) << 3;
        const int s   = c0 + 8 * n16;        // multiple of 8, <= 152
        pA[kk] = row * 192 + (s ^ xr);       // octet [s, s+8)
        pB[kk] = row * 192 + ((s + 8) ^ xr); // octet [s+8, s+16)
    }

    unsigned mask = 0;

#pragma unroll 1
    for (int ft = 0; ft < 4; ++ft) {
        const int fm = ft * 16 + n16;
        half8 wh[8];
        if (PRE) {
            const int fb = (sec * 64 + ft * 16 + n16) * 32 + q;
#pragma unroll
            for (int kk = 0; kk < 8; ++kk) {
                union { uint4 u; half8 h; } c1;
                c1.u = wfh[fb + 4 * kk];
                wh[kk] = c1.h;
            }
        } else {
            // fallback: in-kernel build (used only if ws too small)
#pragma unroll
            for (int kk = 0; kk < 8; ++kk) {
                const int t0 = 32 * kk + 8 * q;
                const bool wvalid = (t0 < 240) && (fm < FM);
                const float* wp = Wg + (size_t)sec * FM * 240 +
                                  (size_t)(wvalid ? fm : 0) * 240 + (wvalid ? t0 : 0);
                float4 wa = *reinterpret_cast<const float4*>(wp);
                float4 wb = *reinterpret_cast<const float4*>(wp + 4);
                float f[8] = {wa.x, wa.y, wa.z, wa.w, wb.x, wb.y, wb.z, wb.w};
                union { unsigned u[4]; half8 h; } c1;
#pragma unroll
                for (int i = 0; i < 4; ++i) {
                    unsigned h0 = f16_bits(wvalid ? f[2 * i] : 0.f);
                    unsigned h1 = f16_bits(wvalid ? f[2 * i + 1] : 0.f);
                    c1.u[i] = (h1 << 16) | h0;
                }
                wh[kk] = c1.h;
            }
        }

#pragma unroll 1
        for (int S = 0; S < 4; ++S) {
            const unsigned short* hb = &xh[S][0][0];

            f32x4 acc0 = {0.f, 0.f, 0.f, 0.f};   // res = S     (off 0)
            f32x4 acc1 = {0.f, 0.f, 0.f, 0.f};   // res = S + 4 (off 4)
#pragma unroll
            for (int kk = 0; kk < 8; ++kk) {
                half8 ah0 = *reinterpret_cast<const half8*>(hb + pA[kk]);
                half4v h1 = *reinterpret_cast<const half4v*>(hb + pB[kk]);
                half8 hx  = __builtin_shufflevector(h1, h1, 0, 1, 2, 3, 0, 1, 2, 3);
                half8 ah1 = __builtin_shufflevector(ah0, hx, 4, 5, 6, 7, 8, 9, 10, 11);
                acc0 = __builtin_amdgcn_mfma_f32_16x16x32_f16(ah0, wh[kk], acc0, 0, 0, 0);
                acc1 = __builtin_amdgcn_mfma_f32_16x16x32_f16(ah1, wh[kk], acc1, 0, 0, 0);
            }

            // ---- epilogue: certain-spike bits + ONE ballot; rare set-only repair ----
            auto epilogue = [&](const f32x4& acc, const int res) {
                float d[4];
                float worst = 1e30f;
#pragma unroll
                for (int reg = 0; reg < 4; ++reg) {
                    const int pcg = w0 + res + 8 * (q * 4 + reg);
                    const bool valid = (fm < FM) && (pcg <= 2007);
                    d[reg] = valid ? __builtin_fabsf(acc[reg] - THRESH) : 1e30f;
                    worst = fminf(worst, d[reg]);
                    if (valid && acc[reg] > THRESH && d[reg] >= MARGIN)  // CERTAIN only
                        mask |= 1u << (reg * 8 + ft * 2 + (res >> 2));
                }
                if (__ballot(worst < MARGIN)) {          // wave-uniform, rare
#pragma unroll
                    for (int reg = 0; reg < 4; ++reg) {
                        unsigned long long bm = __ballot(d[reg] < MARGIN);
                        const unsigned bitv = 1u << (reg * 8 + ft * 2 + (res >> 2));
                        while (bm) {
                            const int src = __ffsll((long long)bm) - 1;
                            bm &= bm - 1;
                            const int q_s   = src >> 4;
                            const int fm_s  = ft * 16 + (src & 15);
                            const int pcg_s = w0 + res + 8 * (q_s * 4 + reg);
                            float part = 0.f;
#pragma unroll
                            for (int k2 = 0; k2 < 4; ++k2) {
                                const int t = L + 64 * k2;
                                if (t < 240) {
                                    const int r2 = t / 40, c2 = t - 40 * r2;
                                    part = fmaf(
                                        x[((size_t)tt * H_ + rowbase + j_p + r2) * WD_ + pcg_s + c2],
                                        Wg[(size_t)sec * FM * 240 + (size_t)fm_s * 240 + t],
                                        part);
                                }
                            }
#pragma unroll
                            for (int off = 32; off; off >>= 1)
                                part += __shfl_xor(part, off);
                            if (L == src && part > THRESH)
                                mask |= bitv;            // SET-ONLY (monotone OR)
                        }
                    }
                }
            };
            epilogue(acc0, S);
            epilogue(acc1, S + 4);
        }
    }

    unsigned* lmask = reinterpret_cast<unsigned*>(sred);
    lmask[j_p * 64 + L] = mask;
    __syncthreads();

    // ---- cross-wave OR + pooled write + fused first-spike argmin ----
    int mykey = 0x7fffffff;
    for (int e = tid; e < 2048; e += 256) {
        const int fmo = e >> 5, p = e & 31;
        const int m = p >> 1, rg = p & 1, ftc = fmo >> 4, fn = fmo & 15;
        const int lane = (m >> 2) * 16 + fn;
        const int bitpos = (m & 3) * 8 + ftc * 2 + rg;
        const unsigned bits = lmask[0 * 64 + lane] | lmask[1 * 64 + lane] |
                              lmask[2 * 64 + lane] | lmask[3 * 64 + lane];
        const int pg = coltile * 32 + p;
        const int spk = (bits >> bitpos) & 1u;
        if (fmo < FM && pg < WP) {
            out[((size_t)(sec * T_ + tt) * FM + fmo) * WP + pg] = spk ? 1.0f : 0.0f;
            if (spk) mykey = min(mykey, fmo * WP + pg);   // section-flat idx
        }
    }
    __syncthreads();                     // protect lmask -> red reuse
    sred[tid] = mykey;
    __syncthreads();
    for (int s = 128; s > 0; s >>= 1) {
        if (tid < s) sred[tid] = min(sred[tid], sred[tid + s]);
        __syncthreads();
    }
    if (tid == 0 && sred[0] != 0x7fffffff)
        atomicMin(&keys[sec], (tt << 15) | sred[0]);
}

// ---------------- init (fallback only) ----------------
__global__ void init_kernel(int* __restrict__ ws)
{
    if (threadIdx.x < NSEC) ws[threadIdx.x] = 0x7fffffff;
}

// ---------------- Kernel D: finalize winners ----------------
__global__ void finalize_kernel(const int* __restrict__ ws, float* __restrict__ out)
{
    const int i = threadIdx.x;
    if (i < NSEC) {
        const int key = ws[i];
        float feat;
        if (key == 0x7fffffff) feat = -1.0f;
        else                   feat = (float)((key & 32767) / WP);
        out[POOLED_SIZE + i] = feat;
    }
}

extern "C" void kernel_launch(void* const* d_in, const int* in_sizes, int n_in,
                              void* d_out, int out_size, void* d_ws, size_t ws_size,
                              hipStream_t stream) {
    const float* x  = (const float*)d_in[0];
    const float* Wg = (const float*)d_in[1];
    float* out = (float*)d_out;
    int*   wsi = (int*)d_ws;
    uint4* wfh = (uint4*)((char*)d_ws + 256);

    const bool pre = ws_size >= 256 + (size_t)NFRAG * 16;   // ~295 KB
    if (pre) {
        prep_kernel<<<dim3(72), dim3(256), 0, stream>>>(Wg, wsi, wfh);
        conv_pool_kernel<true><<<dim3(4320), dim3(256), 0, stream>>>(x, Wg, wfh, out, wsi);
    } else {
        init_kernel<<<dim3(1), dim3(64), 0, stream>>>(wsi);
        conv_pool_kernel<false><<<dim3(4320), dim3(256), 0, stream>>>(x, Wg, wfh, out, wsi);
    }
    finalize_kernel<<<dim3(1), dim3(16), 0, stream>>>(wsi, out);
}

// Round 14
// 166.989 us; speedup vs baseline: 1.1932x; 1.0350x over previous
//
#include <hip/hip_runtime.h>

#define T_ 30
#define H_ 41
#define WD_ 2048
#define NSEC 9
#define FM 50
#define WP 502
#define THRESH 23.0f
#define POOLED_SIZE (NSEC * T_ * FM * WP)   // 6,777,000
#define MARGIN 0.125f                       // >> realistic f16 max error (~0.02)
#define NFRAG 18432                         // 9 sec * 64 fm * 32 tap-octets

typedef _Float16 half8 __attribute__((ext_vector_type(8)));
typedef _Float16 half4v __attribute__((ext_vector_type(4)));
typedef float f32x4 __attribute__((ext_vector_type(4)));

__device__ __forceinline__ unsigned short f16_bits(float f) {
    union { _Float16 h; unsigned short s; } u;
    u.h = (_Float16)f;
    return u.s;
}

// ---------------- prep: W -> MFMA-ready f16 fragments in ws ---------------
__global__ __launch_bounds__(256) void prep_kernel(
    const float* __restrict__ Wg, int* __restrict__ wsi,
    uint4* __restrict__ wfh)
{
    const int gid = blockIdx.x * 256 + threadIdx.x;
    if (gid < NSEC) wsi[gid] = 0x7fffffff;
    if (gid >= NFRAG) return;
    const int blk = gid & 31;
    const int fm  = (gid >> 5) & 63;
    const int sec = gid >> 11;
    const int t0  = blk * 8;
    const bool valid = (t0 < 240) && (fm < FM);
    const float* wp = Wg + ((size_t)sec * FM + (valid ? fm : 0)) * 240 + (valid ? t0 : 0);
    float4 wa = *reinterpret_cast<const float4*>(wp);
    float4 wb = *reinterpret_cast<const float4*>(wp + 4);
    float f[8] = {wa.x, wa.y, wa.z, wa.w, wb.x, wb.y, wb.z, wb.w};
    unsigned hh[4];
#pragma unroll
    for (int i = 0; i < 4; ++i) {
        unsigned h0 = f16_bits(valid ? f[2 * i] : 0.f);
        unsigned h1 = f16_bits(valid ? f[2 * i + 1] : 0.f);
        hh[i] = (h1 << 16) | h0;
    }
    wfh[gid] = *reinterpret_cast<uint4*>(hh);
}

// ---------------- Kernel A: f16 MFMA conv + fire/pool/argmin --------------
// R23 = R22 body (conv ~123us, VGPR 64) with the epilogue stripped to
// wave-mask algebra (~4 VALU/check, was ~8; 128 checks/wave):
//  (1) certain-spike needs NO validity: fm>=FM lanes have zero weights ->
//      acc==0; out-of-range columns (coltile 15, m>=11) set bits that the
//      output loop never reads (pg<WP, fmo<FM guards). `a>=23.125 -> bit`.
//  (2) column validity is res-independent (pcg<=2007 for all res <=>
//      w0+8m<=2000) -> 4 lane-masks via ballot ONCE per kernel (SGPRs).
//  (3) borderline = ballot(a>22.875) & ~ballot(a>=23.125) & fmmask &
//      cmask[reg] -- SALU combines; strict bounds match R20's |a-23|<0.125
//      exactly. Repair unchanged: wave-parallel exact, SET-ONLY (monotone
//      OR, the R19 lesson). Deletes d[]/worst/fmin/per-acc guard ballot and
//      all per-check validity VALU. No new live registers (64 cap, m69).
template <bool PRE>
__global__ __launch_bounds__(256) void conv_pool_kernel(
    const float* __restrict__ x, const float* __restrict__ Wg,
    const uint4* __restrict__ wfh,
    float* __restrict__ out, int* __restrict__ keys)
{
    __shared__ __align__(16) unsigned short xh[4][10][192];   // 15 KB (f16)
    __shared__ int sred[256];                                  // lmask, then red

    const int b       = blockIdx.x;
    const int coltile = b & 15;
    const int tt      = (b >> 4) % T_;
    const int sec     = b / 480;
    const int w0      = coltile * 128;     // pot-col base
    const int rowbase = 4 * sec;
    const int tid     = threadIdx.x;

    // ---- stage x: 10 rows x 176 cols -> f16, 4 shifted planes, swizzled ----
    for (int i = tid; i < 440; i += 256) {
        const int row = i / 44;
        const int c4  = i % 44;
        const int grow = (rowbase + row < H_) ? rowbase + row : H_ - 1;
        const int gc   = w0 + 4 * c4;
        float4 v;
        if (gc + 3 < WD_) {
            v = *reinterpret_cast<const float4*>(x + ((size_t)tt * H_ + grow) * WD_ + gc);
        } else {
            v.x = v.y = v.z = v.w = 0.f;
        }
        float f[4] = {v.x, v.y, v.z, v.w};
        unsigned short hq[4];
#pragma unroll
        for (int e = 0; e < 4; ++e) hq[e] = f16_bits(f[e]);
        const int xr = (row & 7) << 3;
#pragma unroll
        for (int S = 0; S < 4; ++S)
#pragma unroll
            for (int e = 0; e < 4; ++e) {
                const int j = 4 * c4 + e - S;
                if (j >= 0 && j < 176) xh[S][row][j ^ xr] = hq[e];
            }
    }
    __syncthreads();

    const int L    = tid & 63;
    const int j_p  = tid >> 6;       // wave id = pot row
    const int q    = L >> 4;         // quad (K-octet)
    const int n16  = L & 15;         // A: m-index; B: fm-index

    // per-kk tap geometry (tau0 = 32kk + 8q -> weight row r, col c0), swizzled
    int pA[8], pB[8];
#pragma unroll
    for (int kk = 0; kk < 8; ++kk) {
        const int t0 = 32 * kk + 8 * q;
        const int r  = t0 / 40;
        const int c0 = t0 - 40 * r;          // multiple of 8
        const int row = j_p + r;
        const int xr  = (row & 7) << 3;
        const int s   = c0 + 8 * n16;        // multiple of 8, <= 152
        pA[kk] = row * 192 + (s ^ xr);       // octet [s, s+8)
        pB[kk] = row * 192 + ((s + 8) ^ xr); // octet [s+8, s+16)
    }

    // column-validity lane masks (res-independent: pcg<=2007 for all res
    // <=> w0 + 8*(q*4+reg) <= 2000). Wave-uniform -> SGPR pairs, no VGPR.
    unsigned long long cmask[4];
#pragma unroll
    for (int reg = 0; reg < 4; ++reg)
        cmask[reg] = __ballot(w0 + 8 * (q * 4 + reg) <= 2000);

    unsigned mask = 0;

#pragma unroll 1
    for (int ft = 0; ft < 4; ++ft) {
        const int fm = ft * 16 + n16;
        const unsigned long long fmmask = __ballot(fm < FM);
        half8 wh[8];
        if (PRE) {
            const int fb = (sec * 64 + ft * 16 + n16) * 32 + q;
#pragma unroll
            for (int kk = 0; kk < 8; ++kk) {
                union { uint4 u; half8 h; } c1;
                c1.u = wfh[fb + 4 * kk];
                wh[kk] = c1.h;
            }
        } else {
            // fallback: in-kernel build (used only if ws too small)
#pragma unroll
            for (int kk = 0; kk < 8; ++kk) {
                const int t0 = 32 * kk + 8 * q;
                const bool wvalid = (t0 < 240) && (fm < FM);
                const float* wp = Wg + (size_t)sec * FM * 240 +
                                  (size_t)(wvalid ? fm : 0) * 240 + (wvalid ? t0 : 0);
                float4 wa = *reinterpret_cast<const float4*>(wp);
                float4 wb = *reinterpret_cast<const float4*>(wp + 4);
                float f[8] = {wa.x, wa.y, wa.z, wa.w, wb.x, wb.y, wb.z, wb.w};
                union { unsigned u[4]; half8 h; } c1;
#pragma unroll
                for (int i = 0; i < 4; ++i) {
                    unsigned h0 = f16_bits(wvalid ? f[2 * i] : 0.f);
                    unsigned h1 = f16_bits(wvalid ? f[2 * i + 1] : 0.f);
                    c1.u[i] = (h1 << 16) | h0;
                }
                wh[kk] = c1.h;
            }
        }

#pragma unroll 1
        for (int S = 0; S < 4; ++S) {
            const unsigned short* hb = &xh[S][0][0];

            f32x4 acc0 = {0.f, 0.f, 0.f, 0.f};   // res = S     (off 0)
            f32x4 acc1 = {0.f, 0.f, 0.f, 0.f};   // res = S + 4 (off 4)
#pragma unroll
            for (int kk = 0; kk < 8; ++kk) {
                half8 ah0 = *reinterpret_cast<const half8*>(hb + pA[kk]);
                half4v h1 = *reinterpret_cast<const half4v*>(hb + pB[kk]);
                half8 hx  = __builtin_shufflevector(h1, h1, 0, 1, 2, 3, 0, 1, 2, 3);
                half8 ah1 = __builtin_shufflevector(ah0, hx, 4, 5, 6, 7, 8, 9, 10, 11);
                acc0 = __builtin_amdgcn_mfma_f32_16x16x32_f16(ah0, wh[kk], acc0, 0, 0, 0);
                acc1 = __builtin_amdgcn_mfma_f32_16x16x32_f16(ah1, wh[kk], acc1, 0, 0, 0);
            }

            // ---- epilogue: 4-VALU checks; rare set-only repair ----
            auto epilogue = [&](const f32x4& acc, const int res) {
#pragma unroll
                for (int reg = 0; reg < 4; ++reg) {
                    const float a = acc[reg];
                    const unsigned bitv = 1u << (reg * 8 + ft * 2 + (res >> 2));
                    const bool bhi = (a >= THRESH + MARGIN);
                    if (bhi) mask |= bitv;               // certain spike
                    unsigned long long bm =
                        __ballot(a > THRESH - MARGIN) & ~__ballot(bhi) &
                        fmmask & cmask[reg];
                    while (bm) {                          // rare
                        const int src = __ffsll((long long)bm) - 1;
                        bm &= bm - 1;
                        const int q_s   = src >> 4;
                        const int fm_s  = ft * 16 + (src & 15);
                        const int pcg_s = w0 + res + 8 * (q_s * 4 + reg);
                        float part = 0.f;
#pragma unroll
                        for (int k2 = 0; k2 < 4; ++k2) {
                            const int t = L + 64 * k2;
                            if (t < 240) {
                                const int r2 = t / 40, c2 = t - 40 * r2;
                                part = fmaf(
                                    x[((size_t)tt * H_ + rowbase + j_p + r2) * WD_ + pcg_s + c2],
                                    Wg[(size_t)sec * FM * 240 + (size_t)fm_s * 240 + t],
                                    part);
                            }
                        }
#pragma unroll
                        for (int off = 32; off; off >>= 1)
                            part += __shfl_xor(part, off);
                        if (L == src && part > THRESH)
                            mask |= bitv;                // SET-ONLY (monotone OR)
                    }
                }
            };
            epilogue(acc0, S);
            epilogue(acc1, S + 4);
        }
    }

    unsigned* lmask = reinterpret_cast<unsigned*>(sred);
    lmask[j_p * 64 + L] = mask;
    __syncthreads();

    // ---- cross-wave OR + pooled write + fused first-spike argmin ----
    int mykey = 0x7fffffff;
    for (int e = tid; e < 2048; e += 256) {
        const int fmo = e >> 5, p = e & 31;
        const int m = p >> 1, rg = p & 1, ftc = fmo >> 4, fn = fmo & 15;
        const int lane = (m >> 2) * 16 + fn;
        const int bitpos = (m & 3) * 8 + ftc * 2 + rg;
        const unsigned bits = lmask[0 * 64 + lane] | lmask[1 * 64 + lane] |
                              lmask[2 * 64 + lane] | lmask[3 * 64 + lane];
        const int pg = coltile * 32 + p;
        const int spk = (bits >> bitpos) & 1u;
        if (fmo < FM && pg < WP) {
            out[((size_t)(sec * T_ + tt) * FM + fmo) * WP + pg] = spk ? 1.0f : 0.0f;
            if (spk) mykey = min(mykey, fmo * WP + pg);   // section-flat idx
        }
    }
    __syncthreads();                     // protect lmask -> red reuse
    sred[tid] = mykey;
    __syncthreads();
    for (int s = 128; s > 0; s >>= 1) {
        if (tid < s) sred[tid] = min(sred[tid], sred[tid + s]);
        __syncthreads();
    }
    if (tid == 0 && sred[0] != 0x7fffffff)
        atomicMin(&keys[sec], (tt << 15) | sred[0]);
}

// ---------------- init (fallback only) ----------------
__global__ void init_kernel(int* __restrict__ ws)
{
    if (threadIdx.x < NSEC) ws[threadIdx.x] = 0x7fffffff;
}

// ---------------- Kernel D: finalize winners ----------------
__global__ void finalize_kernel(const int* __restrict__ ws, float* __restrict__ out)
{
    const int i = threadIdx.x;
    if (i < NSEC) {
        const int key = ws[i];
        float feat;
        if (key == 0x7fffffff) feat = -1.0f;
        else                   feat = (float)((key & 32767) / WP);
        out[POOLED_SIZE + i] = feat;
    }
}

extern "C" void kernel_launch(void* const* d_in, const int* in_sizes, int n_in,
                              void* d_out, int out_size, void* d_ws, size_t ws_size,
                              hipStream_t stream) {
    const float* x  = (const float*)d_in[0];
    const float* Wg = (const float*)d_in[1];
    float* out = (float*)d_out;
    int*   wsi = (int*)d_ws;
    uint4* wfh = (uint4*)((char*)d_ws + 256);

    const bool pre = ws_size >= 256 + (size_t)NFRAG * 16;   // ~295 KB
    if (pre) {
        prep_kernel<<<dim3(72), dim3(256), 0, stream>>>(Wg, wsi, wfh);
        conv_pool_kernel<true><<<dim3(4320), dim3(256), 0, stream>>>(x, Wg, wfh, out, wsi);
    } else {
        init_kernel<<<dim3(1), dim3(64), 0, stream>>>(wsi);
        conv_pool_kernel<false><<<dim3(4320), dim3(256), 0, stream>>>(x, Wg, wfh, out, wsi);
    }
    finalize_kernel<<<dim3(1), dim3(16), 0, stream>>>(wsi, out);
}